// Round 5
// baseline (241.618 us; speedup 1.0000x reference)
//
#include <hip/hip_runtime.h>
#include <math.h>

#define N_NODES    100000
#define N_EDGES    3200000
#define NUM_GRAPHS 512
#define D_IN       7
#define D_H        16
#define SHIFT      7
#define BWIDTH     128                               // cols per bucket
#define NB         782                               // ceil(N_NODES / BWIDTH)
#define CHUNK      8192
#define NCHUNK     ((N_EDGES + CHUNK - 1) / CHUNK)   // 391

// ---- pass A: exact per-bucket edge counts (LDS-aggregated) ----
__global__ void bin_count_kernel(const int* __restrict__ col, int* __restrict__ bcnt) {
    __shared__ int lh[NB];
    for (int i = threadIdx.x; i < NB; i += blockDim.x) lh[i] = 0;
    __syncthreads();
    int tid = blockIdx.x * blockDim.x + threadIdx.x;
    int stride = gridDim.x * blockDim.x;
    for (int e = tid; e < N_EDGES; e += stride) atomicAdd(&lh[col[e] >> SHIFT], 1);
    __syncthreads();
    for (int i = threadIdx.x; i < NB; i += blockDim.x) {
        int c = lh[i];
        if (c) atomicAdd(&bcnt[i], c);
    }
}

// ---- pass B: exclusive scan -> bucket offsets + cursors (single block) ----
__global__ void scan_kernel(const int* __restrict__ bcnt, int* __restrict__ offs,
                            int* __restrict__ cur) {
    __shared__ int lds[1024];
    int tid = threadIdx.x;
    lds[tid] = (tid < NB) ? bcnt[tid] : 0;
    __syncthreads();
    for (int st = 1; st < 1024; st <<= 1) {
        int v = (tid >= st) ? lds[tid - st] : 0;
        __syncthreads();
        lds[tid] += v;
        __syncthreads();
    }
    if (tid < NB) {
        offs[tid + 1] = lds[tid];
        cur[tid] = (tid == 0) ? 0 : lds[tid - 1];
    }
    if (tid == 0) offs[0] = 0;
}

// ---- pass C: block-level counting sort + coalesced flush.
//      packed word = (row<<7) | (col & 127) ----
__global__ void place_kernel(const int* __restrict__ row, const int* __restrict__ col,
                             int* __restrict__ cur, int* __restrict__ part) {
    __shared__ int sc[1024];        // inclusive scan of per-chunk bucket counts
    __shared__ int lh[NB];          // counts, then local cursors
    __shared__ int lb[NB];          // global base per bucket
    __shared__ int stage[CHUNK];    // bucket-sorted packed edges (32 KB)

    int e0 = blockIdx.x * CHUNK;
    int e1 = e0 + CHUNK; if (e1 > N_EDGES) e1 = N_EDGES;
    int n  = e1 - e0;
    int tid = threadIdx.x;

    for (int i = tid; i < NB; i += blockDim.x) lh[i] = 0;
    __syncthreads();
    // 1. histogram
    for (int e = e0 + tid; e < e1; e += blockDim.x)
        atomicAdd(&lh[col[e] >> SHIFT], 1);
    __syncthreads();
    // 2. inclusive scan (Hillis-Steele over padded 1024)
    for (int i = tid; i < 1024; i += blockDim.x) sc[i] = (i < NB) ? lh[i] : 0;
    __syncthreads();
    for (int st = 1; st < 1024; st <<= 1) {
        int v[4];
        int q = 0;
        for (int i = tid; i < 1024; i += blockDim.x, ++q)
            v[q] = (i >= st) ? sc[i - st] : 0;
        __syncthreads();
        q = 0;
        for (int i = tid; i < 1024; i += blockDim.x, ++q) sc[i] += v[q];
        __syncthreads();
    }
    // 3. reserve global ranges; reset local cursors
    for (int i = tid; i < NB; i += blockDim.x) {
        int c = lh[i];
        lb[i] = c ? atomicAdd(&cur[i], c) : 0;
        lh[i] = 0;
    }
    __syncthreads();
    // 4. scatter into LDS in bucket-sorted order
    for (int e = e0 + tid; e < e1; e += blockDim.x) {
        int cc = col[e];
        int b = cc >> SHIFT;
        int excl = b ? sc[b - 1] : 0;
        int loc = excl + atomicAdd(&lh[b], 1);
        stage[loc] = (row[e] << SHIFT) | (cc & (BWIDTH - 1));
    }
    __syncthreads();
    // 5. coalesced flush: consecutive i -> consecutive dst within bucket runs
    for (int i = tid; i < n; i += blockDim.x) {
        // smallest b with sc[b] > i
        int lo = 0, hi = NB - 1;
        while (lo < hi) {
            int mid = (lo + hi) >> 1;
            if (sc[mid] > i) hi = mid; else lo = mid + 1;
        }
        int excl = lo ? sc[lo - 1] : 0;
        part[lb[lo] + (i - excl)] = stage[i];
    }
}

// ---- pass D: per-bucket CSR build. LDS histogram -> scan -> reorder.
//      Also emits node_off, deg, dinv. Zero global atomics. ----
__global__ void csr_kernel(const int* __restrict__ part, const int* __restrict__ offs,
                           int* __restrict__ csr, int* __restrict__ node_off,
                           int* __restrict__ deg, float* __restrict__ dinv) {
    __shared__ int cnt[BWIDTH];
    __shared__ int scn[BWIDTH];
    __shared__ int cur[BWIDTH];
    int b = blockIdx.x;
    int o0 = offs[b], o1 = offs[b + 1];
    if (threadIdx.x < BWIDTH) cnt[threadIdx.x] = 0;
    __syncthreads();
    for (int j = o0 + threadIdx.x; j < o1; j += blockDim.x)
        atomicAdd(&cnt[part[j] & (BWIDTH - 1)], 1);
    __syncthreads();
    if (threadIdx.x < BWIDTH) scn[threadIdx.x] = cnt[threadIdx.x];
    __syncthreads();
    for (int st = 1; st < BWIDTH; st <<= 1) {
        int v = 0;
        if (threadIdx.x < BWIDTH && threadIdx.x >= st) v = scn[threadIdx.x - st];
        __syncthreads();
        if (threadIdx.x < BWIDTH) scn[threadIdx.x] += v;
        __syncthreads();
    }
    if (threadIdx.x < BWIDTH) {
        int excl = scn[threadIdx.x] - cnt[threadIdx.x];
        cur[threadIdx.x] = excl;
        int c = b * BWIDTH + threadIdx.x;
        if (c < N_NODES) {
            node_off[c] = o0 + excl;
            deg[c] = cnt[threadIdx.x];
            dinv[c] = rsqrtf((float)cnt[threadIdx.x] + 1.0f);   // +1 self-loop
        }
    }
    __syncthreads();
    for (int j = o0 + threadIdx.x; j < o1; j += blockDim.x) {
        int e = part[j];
        int l = e & (BWIDTH - 1);
        int pos = atomicAdd(&cur[l], 1);              // LDS atomic
        csr[o0 + pos] = e >> SHIFT;
    }
}

// s[v,:] = dinv[v] * (x[v,:] @ W1)
__global__ void xw1_kernel(const float* __restrict__ x, const float* __restrict__ W1,
                           const float* __restrict__ dinv, float* __restrict__ s) {
    int v = blockIdx.x * blockDim.x + threadIdx.x;
    if (v >= N_NODES) return;
    float xv[D_IN];
#pragma unroll
    for (int j = 0; j < D_IN; ++j) xv[j] = x[v * D_IN + j];
    float dv = dinv[v];
#pragma unroll
    for (int k = 0; k < D_H; ++k) {
        float a = 0.f;
#pragma unroll
        for (int j = 0; j < D_IN; ++j) a += xv[j] * W1[j * D_H + k];
        s[v * D_H + k] = a * dv;
    }
}

// s[v,:] = dinv[v] * (h[v,:] @ W2)
__global__ void hw2_kernel(const float* __restrict__ h, const float* __restrict__ W2,
                           const float* __restrict__ dinv, float* __restrict__ s) {
    int v = blockIdx.x * blockDim.x + threadIdx.x;
    if (v >= N_NODES) return;
    float hv[D_H];
#pragma unroll
    for (int j = 0; j < D_H; ++j) hv[j] = h[v * D_H + j];
    float dv = dinv[v];
#pragma unroll
    for (int k = 0; k < D_H; ++k) {
        float a = 0.f;
#pragma unroll
        for (int j = 0; j < D_H; ++j) a += hv[j] * W2[j * D_H + k];
        s[v * D_H + k] = a * dv;
    }
}

// pull-gather + finalize: one wave per node; 4 edge-slots x 16 features, 4-deep.
// h[v,k] = relu(dinv[v]*(sum_r s[r,k] + s[v,k]) + b[k])
__global__ void pull_kernel(const float* __restrict__ s, const int* __restrict__ csr,
                            const int* __restrict__ node_off, const int* __restrict__ deg,
                            const float* __restrict__ dinv, const float* __restrict__ b,
                            float* __restrict__ h) {
    int wave = threadIdx.x >> 6;            // 4 waves per block
    int v = blockIdx.x * 4 + wave;
    if (v >= N_NODES) return;
    int lane = threadIdx.x & 63;
    int sub = lane >> 4;                    // 0..3 edge-slot group
    int k   = lane & 15;                    // feature
    int d   = deg[v];
    int o0  = node_off[v];
    float acc = 0.f;
    int j = sub;
    for (; j + 12 < d; j += 16) {           // 4 lines in flight
        int r1 = csr[o0 + j];
        int r2 = csr[o0 + j + 4];
        int r3 = csr[o0 + j + 8];
        int r4 = csr[o0 + j + 12];
        float v1 = s[r1 * D_H + k];
        float v2 = s[r2 * D_H + k];
        float v3 = s[r3 * D_H + k];
        float v4 = s[r4 * D_H + k];
        acc += (v1 + v2) + (v3 + v4);
    }
    for (; j < d; j += 4) acc += s[csr[o0 + j] * D_H + k];
    acc += __shfl_xor(acc, 16, 64);
    acc += __shfl_xor(acc, 32, 64);
    if (sub == 0) {
        float o = dinv[v] * (acc + s[v * D_H + k]) + b[k];
        h[v * D_H + k] = fmaxf(o, 0.f);
    }
}

// batch sorted: starts[g] = first node of graph g; starts[NUM_GRAPHS] = N
__global__ void starts_kernel(const int* __restrict__ batch, int* __restrict__ starts) {
    int v = blockIdx.x * blockDim.x + threadIdx.x;
    if (v >= N_NODES) return;
    int bv = batch[v];
    int prev = (v == 0) ? -1 : batch[v - 1];
    for (int g = prev + 1; g <= bv; ++g) starts[g] = v;
    if (v == N_NODES - 1) {
        for (int g = bv + 1; g <= NUM_GRAPHS; ++g) starts[g] = N_NODES;
    }
}

// one block per graph: mean-pool h rows then sigmoid(pool @ Wl + bl)
__global__ void pool_head_kernel(const float* __restrict__ h, const int* __restrict__ starts,
                                 const float* __restrict__ Wl, const float* __restrict__ bl,
                                 float* __restrict__ out) {
    int g = blockIdx.x;
    int v0 = starts[g], v1 = starts[g + 1];
    int k = threadIdx.x & 15;
    int vi = threadIdx.x >> 4;
    float acc = 0.f;
    for (int v = v0 + vi; v < v1; v += 16) acc += h[v * D_H + k];
    acc += __shfl_xor(acc, 16, 64);
    acc += __shfl_xor(acc, 32, 64);
    __shared__ float sm[4][D_H];
    int lane = threadIdx.x & 63;
    if (lane < 16) sm[threadIdx.x >> 6][k] = acc;
    __syncthreads();
    if (threadIdx.x < 16) {
        float tot = sm[0][k] + sm[1][k] + sm[2][k] + sm[3][k];
        float cntf = (float)(v1 - v0);
        tot /= fmaxf(cntf, 1.0f);
        float p = tot * Wl[k];
        p += __shfl_xor(p, 1, 64);
        p += __shfl_xor(p, 2, 64);
        p += __shfl_xor(p, 4, 64);
        p += __shfl_xor(p, 8, 64);
        if (k == 0) out[g] = 1.0f / (1.0f + expf(-(p + bl[0])));
    }
}

// ---------------- launch ----------------

extern "C" void kernel_launch(void* const* d_in, const int* in_sizes, int n_in,
                              void* d_out, int out_size, void* d_ws, size_t ws_size,
                              hipStream_t stream) {
    const float* x     = (const float*)d_in[0];
    const int*   ei    = (const int*)d_in[1];   // [2, E]: row then col
    const int*   batch = (const int*)d_in[2];
    const float* W1    = (const float*)d_in[3];
    const float* b1    = (const float*)d_in[4];
    const float* W2    = (const float*)d_in[5];
    const float* b2    = (const float*)d_in[6];
    const float* Wl    = (const float*)d_in[7];
    const float* bl    = (const float*)d_in[8];
    float* out = (float*)d_out;

    const int* row = ei;
    const int* col = ei + N_EDGES;

    // workspace layout (4-byte words), ~40 MB total
    char* wsb = (char*)d_ws;
    size_t o = 0;
    int*   part     = (int*)(wsb + o);   o += (size_t)N_EDGES * 4;   // 12.8 MB
    int*   csr      = (int*)(wsb + o);   o += (size_t)N_EDGES * 4;   // 12.8 MB
    int*   bcnt     = (int*)(wsb + o);   o += 1024 * 4;
    int*   offs     = (int*)(wsb + o);   o += 1024 * 4;
    int*   cur      = (int*)(wsb + o);   o += 1024 * 4;
    int*   node_off = (int*)(wsb + o);   o += 100352 * 4;
    int*   deg      = (int*)(wsb + o);   o += 100352 * 4;
    float* dinv     = (float*)(wsb + o); o += 100352 * 4;
    float* s        = (float*)(wsb + o); o += (size_t)N_NODES * D_H * 4;
    float* h        = (float*)(wsb + o); o += (size_t)N_NODES * D_H * 4;
    int*   starts   = (int*)(wsb + o);   o += 1024 * 4;

    const int B = 256;
    const int NVB = (N_NODES + B - 1) / B;   // 391

    // ---- build bucket-partition then CSR (no per-edge global atomics) ----
    hipMemsetAsync(bcnt, 0, NB * sizeof(int), stream);
    bin_count_kernel<<<512, B, 0, stream>>>(col, bcnt);
    scan_kernel<<<1, 1024, 0, stream>>>(bcnt, offs, cur);
    place_kernel<<<NCHUNK, B, 0, stream>>>(row, col, cur, part);
    csr_kernel<<<NB, B, 0, stream>>>(part, offs, csr, node_off, deg, dinv);

    // ---- layer 1 ----
    xw1_kernel<<<NVB, B, 0, stream>>>(x, W1, dinv, s);
    pull_kernel<<<(N_NODES + 3) / 4, B, 0, stream>>>(s, csr, node_off, deg, dinv, b1, h);

    // ---- layer 2 ----
    hw2_kernel<<<NVB, B, 0, stream>>>(h, W2, dinv, s);
    pull_kernel<<<(N_NODES + 3) / 4, B, 0, stream>>>(s, csr, node_off, deg, dinv, b2, h);

    // ---- pool + head ----
    starts_kernel<<<NVB, B, 0, stream>>>(batch, starts);
    pool_head_kernel<<<NUM_GRAPHS, B, 0, stream>>>(h, starts, Wl, bl, out);
}

// Round 6
// 218.548 us; speedup vs baseline: 1.1056x; 1.1056x over previous
//
#include <hip/hip_runtime.h>
#include <math.h>

#define N_NODES    100000
#define N_EDGES    3200000
#define NUM_GRAPHS 512
#define D_IN       7
#define D_H        16
#define SHIFT      7
#define BWIDTH     128                         // cols per bucket
#define NB         782                         // ceil(N_NODES / BWIDTH)
#define CHUNK      2048
#define NCH        1563                        // ceil(N_EDGES / CHUNK)
#define PC         7                           // ceil(NCH / 256)

// ---- pass A: per-chunk bucket histograms. cnt[chunk][bucket], coalesced rows ----
__global__ void hist_kernel(const int* __restrict__ col, int* __restrict__ cnt) {
    __shared__ int lh[NB];
    int tid = threadIdx.x;
    for (int i = tid; i < NB; i += blockDim.x) lh[i] = 0;
    __syncthreads();
    int e0 = blockIdx.x * CHUNK;
    int e1 = e0 + CHUNK; if (e1 > N_EDGES) e1 = N_EDGES;
    for (int e = e0 + tid; e < e1; e += blockDim.x)
        atomicAdd(&lh[col[e] >> SHIFT], 1);
    __syncthreads();
    int* outp = cnt + (size_t)blockIdx.x * NB;
    for (int i = tid; i < NB; i += blockDim.x) outp[i] = lh[i];
}

// ---- pass B: per-bucket exclusive scan over chunks.
//      base[bucket][chunk] (coalesced writes), bcnt[bucket] = total ----
__global__ void colscan_kernel(const int* __restrict__ cnt, int* __restrict__ base,
                               int* __restrict__ bcnt) {
    __shared__ int ts[256];
    int b = blockIdx.x;
    int tid = threadIdx.x;
    int c0 = tid * PC;
    int vals[PC];
    int sum = 0;
#pragma unroll
    for (int q = 0; q < PC; ++q) {
        int c = c0 + q;
        int v = (c < NCH) ? cnt[(size_t)c * NB + b] : 0;
        vals[q] = v; sum += v;
    }
    ts[tid] = sum;
    __syncthreads();
    for (int st = 1; st < 256; st <<= 1) {
        int v = (tid >= st) ? ts[tid - st] : 0;
        __syncthreads();
        ts[tid] += v;
        __syncthreads();
    }
    int run = ts[tid] - sum;                       // exclusive prefix
    int* bp = base + (size_t)b * NCH;
#pragma unroll
    for (int q = 0; q < PC; ++q) {
        int c = c0 + q;
        if (c < NCH) { bp[c] = run; run += vals[q]; }
    }
    if (tid == 0) bcnt[b] = ts[255];
}

// ---- pass C: exclusive scan of bucket totals -> offs (single block) ----
__global__ void scan_kernel(const int* __restrict__ bcnt, int* __restrict__ offs) {
    __shared__ int lds[1024];
    int tid = threadIdx.x;
    lds[tid] = (tid < NB) ? bcnt[tid] : 0;
    __syncthreads();
    for (int st = 1; st < 1024; st <<= 1) {
        int v = (tid >= st) ? lds[tid - st] : 0;
        __syncthreads();
        lds[tid] += v;
        __syncthreads();
    }
    if (tid < NB) offs[tid + 1] = lds[tid];
    if (tid == 0) offs[0] = 0;
}

// ---- pass D: place. Destinations fully precomputed; LDS cursors only.
//      packed word = (row<<7) | (col & 127) ----
__global__ void place_kernel(const int* __restrict__ row, const int* __restrict__ col,
                             const int* __restrict__ base, const int* __restrict__ offs,
                             int* __restrict__ part) {
    __shared__ int cur[NB];
    int c = blockIdx.x;
    int tid = threadIdx.x;
    for (int b = tid; b < NB; b += blockDim.x)
        cur[b] = offs[b] + base[(size_t)b * NCH + c];
    __syncthreads();
    int e0 = c * CHUNK;
    int e1 = e0 + CHUNK; if (e1 > N_EDGES) e1 = N_EDGES;
    for (int e = e0 + tid; e < e1; e += blockDim.x) {
        int cc = col[e];
        int b = cc >> SHIFT;
        int pos = atomicAdd(&cur[b], 1);           // LDS atomic
        part[pos] = (row[e] << SHIFT) | (cc & (BWIDTH - 1));
    }
}

// ---- pass E: per-bucket CSR build + node_off/deg/dinv. Zero global atomics ----
__global__ void csr_kernel(const int* __restrict__ part, const int* __restrict__ offs,
                           int* __restrict__ csr, int* __restrict__ node_off,
                           int* __restrict__ deg, float* __restrict__ dinv) {
    __shared__ int cnt[BWIDTH];
    __shared__ int scn[BWIDTH];
    __shared__ int cur[BWIDTH];
    int b = blockIdx.x;
    int o0 = offs[b], o1 = offs[b + 1];
    if (threadIdx.x < BWIDTH) cnt[threadIdx.x] = 0;
    __syncthreads();
    for (int j = o0 + threadIdx.x; j < o1; j += blockDim.x)
        atomicAdd(&cnt[part[j] & (BWIDTH - 1)], 1);
    __syncthreads();
    if (threadIdx.x < BWIDTH) scn[threadIdx.x] = cnt[threadIdx.x];
    __syncthreads();
    for (int st = 1; st < BWIDTH; st <<= 1) {
        int v = 0;
        if (threadIdx.x < BWIDTH && threadIdx.x >= st) v = scn[threadIdx.x - st];
        __syncthreads();
        if (threadIdx.x < BWIDTH) scn[threadIdx.x] += v;
        __syncthreads();
    }
    if (threadIdx.x < BWIDTH) {
        int excl = scn[threadIdx.x] - cnt[threadIdx.x];
        cur[threadIdx.x] = excl;
        int c = b * BWIDTH + threadIdx.x;
        if (c < N_NODES) {
            node_off[c] = o0 + excl;
            deg[c] = cnt[threadIdx.x];
            dinv[c] = rsqrtf((float)cnt[threadIdx.x] + 1.0f);   // +1 self-loop
        }
    }
    __syncthreads();
    for (int j = o0 + threadIdx.x; j < o1; j += blockDim.x) {
        int e = part[j];
        int l = e & (BWIDTH - 1);
        int pos = atomicAdd(&cur[l], 1);           // LDS atomic
        csr[o0 + pos] = e >> SHIFT;
    }
}

// s[v,:] = dinv[v] * (x[v,:] @ W1)
__global__ void xw1_kernel(const float* __restrict__ x, const float* __restrict__ W1,
                           const float* __restrict__ dinv, float* __restrict__ s) {
    int v = blockIdx.x * blockDim.x + threadIdx.x;
    if (v >= N_NODES) return;
    float xv[D_IN];
#pragma unroll
    for (int j = 0; j < D_IN; ++j) xv[j] = x[v * D_IN + j];
    float dv = dinv[v];
#pragma unroll
    for (int k = 0; k < D_H; ++k) {
        float a = 0.f;
#pragma unroll
        for (int j = 0; j < D_IN; ++j) a += xv[j] * W1[j * D_H + k];
        s[v * D_H + k] = a * dv;
    }
}

// layer-1 pull + fused layer-2 GEMM epilogue:
// h = relu(dinv*(gather+self)+b1);  s2[v,k] = dinv[v] * sum_j h[j]*W2[j,k]
__global__ void pull1_kernel(const float* __restrict__ s, const int* __restrict__ csr,
                             const int* __restrict__ node_off, const int* __restrict__ deg,
                             const float* __restrict__ dinv, const float* __restrict__ b1,
                             const float* __restrict__ W2, float* __restrict__ s2) {
    int wave = threadIdx.x >> 6;
    int v = blockIdx.x * 4 + wave;
    if (v >= N_NODES) return;
    int lane = threadIdx.x & 63;
    int sub = lane >> 4;
    int k   = lane & 15;
    float w2c[D_H];                          // W2 column k, preloaded (L1-cached)
#pragma unroll
    for (int j = 0; j < D_H; ++j) w2c[j] = W2[j * D_H + k];
    int d  = deg[v];
    int o0 = node_off[v];
    float acc = 0.f;
    int j = sub;
    for (; j + 12 < d; j += 16) {            // 4 lines in flight
        int r1 = csr[o0 + j];
        int r2 = csr[o0 + j + 4];
        int r3 = csr[o0 + j + 8];
        int r4 = csr[o0 + j + 12];
        float v1 = s[r1 * D_H + k];
        float v2 = s[r2 * D_H + k];
        float v3 = s[r3 * D_H + k];
        float v4 = s[r4 * D_H + k];
        acc += (v1 + v2) + (v3 + v4);
    }
    for (; j < d; j += 4) acc += s[csr[o0 + j] * D_H + k];
    acc += __shfl_xor(acc, 16, 64);
    acc += __shfl_xor(acc, 32, 64);          // all lanes hold full sum
    float dv = dinv[v];
    float h = fmaxf(dv * (acc + s[v * D_H + k]) + b1[k], 0.f);
    // h[v,k] lives in lane (sub*16+k), identical across subs
    float a2 = 0.f;
#pragma unroll
    for (int jj = 0; jj < D_H; ++jj) {
        float hj = __shfl(h, (lane & 48) + jj, 64);
        a2 += hj * w2c[jj];
    }
    if (sub == 0) s2[v * D_H + k] = a2 * dv;
}

// layer-2 pull: h2 = relu(dinv*(gather+self)+b2)
__global__ void pull2_kernel(const float* __restrict__ s, const int* __restrict__ csr,
                             const int* __restrict__ node_off, const int* __restrict__ deg,
                             const float* __restrict__ dinv, const float* __restrict__ b2,
                             float* __restrict__ h) {
    int wave = threadIdx.x >> 6;
    int v = blockIdx.x * 4 + wave;
    if (v >= N_NODES) return;
    int lane = threadIdx.x & 63;
    int sub = lane >> 4;
    int k   = lane & 15;
    int d  = deg[v];
    int o0 = node_off[v];
    float acc = 0.f;
    int j = sub;
    for (; j + 12 < d; j += 16) {
        int r1 = csr[o0 + j];
        int r2 = csr[o0 + j + 4];
        int r3 = csr[o0 + j + 8];
        int r4 = csr[o0 + j + 12];
        float v1 = s[r1 * D_H + k];
        float v2 = s[r2 * D_H + k];
        float v3 = s[r3 * D_H + k];
        float v4 = s[r4 * D_H + k];
        acc += (v1 + v2) + (v3 + v4);
    }
    for (; j < d; j += 4) acc += s[csr[o0 + j] * D_H + k];
    acc += __shfl_xor(acc, 16, 64);
    acc += __shfl_xor(acc, 32, 64);
    if (sub == 0) {
        float o = dinv[v] * (acc + s[v * D_H + k]) + b2[k];
        h[v * D_H + k] = fmaxf(o, 0.f);
    }
}

// batch sorted: starts[g] = first node of graph g; starts[NUM_GRAPHS] = N
__global__ void starts_kernel(const int* __restrict__ batch, int* __restrict__ starts) {
    int v = blockIdx.x * blockDim.x + threadIdx.x;
    if (v >= N_NODES) return;
    int bv = batch[v];
    int prev = (v == 0) ? -1 : batch[v - 1];
    for (int g = prev + 1; g <= bv; ++g) starts[g] = v;
    if (v == N_NODES - 1) {
        for (int g = bv + 1; g <= NUM_GRAPHS; ++g) starts[g] = N_NODES;
    }
}

// one block per graph: mean-pool h rows then sigmoid(pool @ Wl + bl)
__global__ void pool_head_kernel(const float* __restrict__ h, const int* __restrict__ starts,
                                 const float* __restrict__ Wl, const float* __restrict__ bl,
                                 float* __restrict__ out) {
    int g = blockIdx.x;
    int v0 = starts[g], v1 = starts[g + 1];
    int k = threadIdx.x & 15;
    int vi = threadIdx.x >> 4;
    float acc = 0.f;
    for (int v = v0 + vi; v < v1; v += 16) acc += h[v * D_H + k];
    acc += __shfl_xor(acc, 16, 64);
    acc += __shfl_xor(acc, 32, 64);
    __shared__ float sm[4][D_H];
    int lane = threadIdx.x & 63;
    if (lane < 16) sm[threadIdx.x >> 6][k] = acc;
    __syncthreads();
    if (threadIdx.x < 16) {
        float tot = sm[0][k] + sm[1][k] + sm[2][k] + sm[3][k];
        float cntf = (float)(v1 - v0);
        tot /= fmaxf(cntf, 1.0f);
        float p = tot * Wl[k];
        p += __shfl_xor(p, 1, 64);
        p += __shfl_xor(p, 2, 64);
        p += __shfl_xor(p, 4, 64);
        p += __shfl_xor(p, 8, 64);
        if (k == 0) out[g] = 1.0f / (1.0f + expf(-(p + bl[0])));
    }
}

// ---------------- launch ----------------

extern "C" void kernel_launch(void* const* d_in, const int* in_sizes, int n_in,
                              void* d_out, int out_size, void* d_ws, size_t ws_size,
                              hipStream_t stream) {
    const float* x     = (const float*)d_in[0];
    const int*   ei    = (const int*)d_in[1];   // [2, E]: row then col
    const int*   batch = (const int*)d_in[2];
    const float* W1    = (const float*)d_in[3];
    const float* b1    = (const float*)d_in[4];
    const float* W2    = (const float*)d_in[5];
    const float* b2    = (const float*)d_in[6];
    const float* Wl    = (const float*)d_in[7];
    const float* bl    = (const float*)d_in[8];
    float* out = (float*)d_out;

    const int* row = ei;
    const int* col = ei + N_EDGES;

    // workspace layout. Region A is time-shared: {cnt+base} then csr.
    char* wsb = (char*)d_ws;
    size_t o = 0;
    int*   part     = (int*)(wsb + o);   o += (size_t)N_EDGES * 4;          // 12.8 MB
    char*  regionA  = wsb + o;           o += (size_t)N_EDGES * 4;          // 12.8 MB
    int*   cnt      = (int*)regionA;                                        // [NCH][NB]
    int*   base     = (int*)(regionA + (size_t)NCH * NB * 4);               // [NB][NCH]
    int*   csr      = (int*)regionA;                                        // after place
    int*   bcnt     = (int*)(wsb + o);   o += 1024 * 4;
    int*   offs     = (int*)(wsb + o);   o += 1024 * 4;
    int*   node_off = (int*)(wsb + o);   o += 100352 * 4;
    int*   deg      = (int*)(wsb + o);   o += 100352 * 4;
    float* dinv     = (float*)(wsb + o); o += 100352 * 4;
    float* sA       = (float*)(wsb + o); o += (size_t)N_NODES * D_H * 4;    // 6.4 MB
    float* sB       = (float*)(wsb + o); o += (size_t)N_NODES * D_H * 4;    // 6.4 MB
    int*   starts   = (int*)(wsb + o);   o += 1024 * 4;

    const int B = 256;
    const int NVB = (N_NODES + B - 1) / B;   // 391

    // ---- build CSR via deterministic two-level scan (no global cursor atomics) ----
    hist_kernel<<<NCH, B, 0, stream>>>(col, cnt);
    colscan_kernel<<<NB, B, 0, stream>>>(cnt, base, bcnt);
    scan_kernel<<<1, 1024, 0, stream>>>(bcnt, offs);
    place_kernel<<<NCH, B, 0, stream>>>(row, col, base, offs, part);
    csr_kernel<<<NB, B, 0, stream>>>(part, offs, csr, node_off, deg, dinv);

    // ---- layer 1 (+ fused layer-2 GEMM) ----
    xw1_kernel<<<NVB, B, 0, stream>>>(x, W1, dinv, sA);
    pull1_kernel<<<(N_NODES + 3) / 4, B, 0, stream>>>(sA, csr, node_off, deg, dinv,
                                                      b1, W2, sB);
    // ---- layer 2 (h2 reuses sA) ----
    pull2_kernel<<<(N_NODES + 3) / 4, B, 0, stream>>>(sB, csr, node_off, deg, dinv,
                                                      b2, sA);
    // ---- pool + head ----
    starts_kernel<<<NVB, B, 0, stream>>>(batch, starts);
    pool_head_kernel<<<NUM_GRAPHS, B, 0, stream>>>(sA, starts, Wl, bl, out);
}

// Round 7
// 207.500 us; speedup vs baseline: 1.1644x; 1.0532x over previous
//
#include <hip/hip_runtime.h>
#include <math.h>

#define N_NODES    100000
#define N_EDGES    3200000
#define NUM_GRAPHS 512
#define D_IN       7
#define D_H        16
#define SHIFT      7
#define BWIDTH     128                         // cols per bucket
#define NB         782                         // ceil(N_NODES / BWIDTH)
#define CHUNK      2048
#define NCH        1563                        // ceil(N_EDGES / CHUNK)
#define PC         7                           // ceil(NCH / 256)
#define PB         4                           // ceil(NB / 256) buckets per thread

// ---- pass A: per-chunk bucket histograms. cnt[chunk][bucket], coalesced rows ----
__global__ void hist_kernel(const int* __restrict__ col, int* __restrict__ cnt) {
    __shared__ int lh[NB];
    int tid = threadIdx.x;
    for (int i = tid; i < NB; i += blockDim.x) lh[i] = 0;
    __syncthreads();
    int e0 = blockIdx.x * CHUNK;
    int e1 = e0 + CHUNK; if (e1 > N_EDGES) e1 = N_EDGES;
    for (int e = e0 + tid; e < e1; e += blockDim.x)
        atomicAdd(&lh[col[e] >> SHIFT], 1);
    __syncthreads();
    int* outp = cnt + (size_t)blockIdx.x * NB;
    for (int i = tid; i < NB; i += blockDim.x) outp[i] = lh[i];
}

// ---- pass B: per-bucket exclusive scan over chunks.
//      base[bucket][chunk] (coalesced writes), bcnt[bucket] = total ----
__global__ void colscan_kernel(const int* __restrict__ cnt, int* __restrict__ base,
                               int* __restrict__ bcnt) {
    __shared__ int ts[256];
    int b = blockIdx.x;
    int tid = threadIdx.x;
    int c0 = tid * PC;
    int vals[PC];
    int sum = 0;
#pragma unroll
    for (int q = 0; q < PC; ++q) {
        int c = c0 + q;
        int v = (c < NCH) ? cnt[(size_t)c * NB + b] : 0;
        vals[q] = v; sum += v;
    }
    ts[tid] = sum;
    __syncthreads();
    for (int st = 1; st < 256; st <<= 1) {
        int v = (tid >= st) ? ts[tid - st] : 0;
        __syncthreads();
        ts[tid] += v;
        __syncthreads();
    }
    int run = ts[tid] - sum;                       // exclusive prefix
    int* bp = base + (size_t)b * NCH;
#pragma unroll
    for (int q = 0; q < PC; ++q) {
        int c = c0 + q;
        if (c < NCH) { bp[c] = run; run += vals[q]; }
    }
    if (tid == 0) bcnt[b] = ts[255];
}

// ---- pass C: exclusive scan of bucket totals -> offs (single block) ----
__global__ void scan_kernel(const int* __restrict__ bcnt, int* __restrict__ offs) {
    __shared__ int lds[1024];
    int tid = threadIdx.x;
    lds[tid] = (tid < NB) ? bcnt[tid] : 0;
    __syncthreads();
    for (int st = 1; st < 1024; st <<= 1) {
        int v = (tid >= st) ? lds[tid - st] : 0;
        __syncthreads();
        lds[tid] += v;
        __syncthreads();
    }
    if (tid < NB) offs[tid + 1] = lds[tid];
    if (tid == 0) offs[0] = 0;
}

// ---- pass D: place with LDS staging + precomputed destinations + coalesced flush.
//      packed word = (row<<7) | (col & 127) ----
__global__ void place_kernel(const int* __restrict__ row, const int* __restrict__ col,
                             const int* __restrict__ base, const int* __restrict__ offs,
                             int* __restrict__ part) {
    __shared__ int lh[NB];          // counts, then cursors
    __shared__ int sc[NB];          // within-chunk exclusive base per bucket
    __shared__ int lb[NB];          // global base per bucket for this chunk
    __shared__ int ts[256];
    __shared__ int stage[CHUNK];    // bucket-sorted packed edges (8 KB)
    __shared__ int dstv[CHUNK];     // precomputed global destination (8 KB)

    int c = blockIdx.x;
    int tid = threadIdx.x;
    int e0 = c * CHUNK;
    int e1 = e0 + CHUNK; if (e1 > N_EDGES) e1 = N_EDGES;
    int n  = e1 - e0;

    for (int i = tid; i < NB; i += blockDim.x) lh[i] = 0;
    __syncthreads();
    // 1. histogram
    for (int e = e0 + tid; e < e1; e += blockDim.x)
        atomicAdd(&lh[col[e] >> SHIFT], 1);
    __syncthreads();
    // 2. cheap scan: thread owns PB consecutive buckets
    int b0 = tid * PB;
    int vals[PB];
    int sum = 0;
#pragma unroll
    for (int q = 0; q < PB; ++q) {
        int b = b0 + q;
        int v = (b < NB) ? lh[b] : 0;
        vals[q] = v; sum += v;
    }
    ts[tid] = sum;
    __syncthreads();
    for (int st = 1; st < 256; st <<= 1) {
        int v = (tid >= st) ? ts[tid - st] : 0;
        __syncthreads();
        ts[tid] += v;
        __syncthreads();
    }
    int run = ts[tid] - sum;
#pragma unroll
    for (int q = 0; q < PB; ++q) {
        int b = b0 + q;
        if (b < NB) {
            sc[b] = run;
            lb[b] = offs[b] + base[(size_t)b * NCH + c];
            run += vals[q];
            lh[b] = 0;              // reset cursor
        }
    }
    __syncthreads();
    // 3. scatter into LDS sorted by bucket; record final destination
    for (int e = e0 + tid; e < e1; e += blockDim.x) {
        int cc = col[e];
        int b = cc >> SHIFT;
        int rank = atomicAdd(&lh[b], 1);           // LDS atomic
        int loc = sc[b] + rank;
        stage[loc] = (row[e] << SHIFT) | (cc & (BWIDTH - 1));
        dstv[loc]  = lb[b] + rank;
    }
    __syncthreads();
    // 4. coalesced flush: consecutive i -> consecutive dst within bucket runs
    for (int i = tid; i < n; i += blockDim.x)
        part[dstv[i]] = stage[i];
}

// ---- pass E: per-bucket CSR build + node_off/deg/dinv. Zero global atomics ----
__global__ void csr_kernel(const int* __restrict__ part, const int* __restrict__ offs,
                           int* __restrict__ csr, int* __restrict__ node_off,
                           int* __restrict__ deg, float* __restrict__ dinv) {
    __shared__ int cnt[BWIDTH];
    __shared__ int scn[BWIDTH];
    __shared__ int cur[BWIDTH];
    int b = blockIdx.x;
    int o0 = offs[b], o1 = offs[b + 1];
    if (threadIdx.x < BWIDTH) cnt[threadIdx.x] = 0;
    __syncthreads();
    for (int j = o0 + threadIdx.x; j < o1; j += blockDim.x)
        atomicAdd(&cnt[part[j] & (BWIDTH - 1)], 1);
    __syncthreads();
    if (threadIdx.x < BWIDTH) scn[threadIdx.x] = cnt[threadIdx.x];
    __syncthreads();
    for (int st = 1; st < BWIDTH; st <<= 1) {
        int v = 0;
        if (threadIdx.x < BWIDTH && threadIdx.x >= st) v = scn[threadIdx.x - st];
        __syncthreads();
        if (threadIdx.x < BWIDTH) scn[threadIdx.x] += v;
        __syncthreads();
    }
    if (threadIdx.x < BWIDTH) {
        int excl = scn[threadIdx.x] - cnt[threadIdx.x];
        cur[threadIdx.x] = excl;
        int c = b * BWIDTH + threadIdx.x;
        if (c < N_NODES) {
            node_off[c] = o0 + excl;
            deg[c] = cnt[threadIdx.x];
            dinv[c] = rsqrtf((float)cnt[threadIdx.x] + 1.0f);   // +1 self-loop
        }
    }
    __syncthreads();
    for (int j = o0 + threadIdx.x; j < o1; j += blockDim.x) {
        int e = part[j];
        int l = e & (BWIDTH - 1);
        int pos = atomicAdd(&cur[l], 1);           // LDS atomic
        csr[o0 + pos] = e >> SHIFT;
    }
}

// s[v,:] = dinv[v] * (x[v,:] @ W1)
__global__ void xw1_kernel(const float* __restrict__ x, const float* __restrict__ W1,
                           const float* __restrict__ dinv, float* __restrict__ s) {
    int v = blockIdx.x * blockDim.x + threadIdx.x;
    if (v >= N_NODES) return;
    float xv[D_IN];
#pragma unroll
    for (int j = 0; j < D_IN; ++j) xv[j] = x[v * D_IN + j];
    float dv = dinv[v];
#pragma unroll
    for (int k = 0; k < D_H; ++k) {
        float a = 0.f;
#pragma unroll
        for (int j = 0; j < D_IN; ++j) a += xv[j] * W1[j * D_H + k];
        s[v * D_H + k] = a * dv;
    }
}

// layer-1 pull + fused layer-2 GEMM epilogue:
// h = relu(dinv*(gather+self)+b1);  s2[v,k] = dinv[v] * sum_j h[j]*W2[j,k]
__global__ void pull1_kernel(const float* __restrict__ s, const int* __restrict__ csr,
                             const int* __restrict__ node_off, const int* __restrict__ deg,
                             const float* __restrict__ dinv, const float* __restrict__ b1,
                             const float* __restrict__ W2, float* __restrict__ s2) {
    int wave = threadIdx.x >> 6;
    int v = blockIdx.x * 4 + wave;
    if (v >= N_NODES) return;
    int lane = threadIdx.x & 63;
    int sub = lane >> 4;
    int k   = lane & 15;
    float w2c[D_H];                          // W2 column k, preloaded (L1-cached)
#pragma unroll
    for (int j = 0; j < D_H; ++j) w2c[j] = W2[j * D_H + k];
    int d  = deg[v];
    int o0 = node_off[v];
    float acc = 0.f;
    int j = sub;
    for (; j + 12 < d; j += 16) {            // 4 lines in flight
        int r1 = csr[o0 + j];
        int r2 = csr[o0 + j + 4];
        int r3 = csr[o0 + j + 8];
        int r4 = csr[o0 + j + 12];
        float v1 = s[r1 * D_H + k];
        float v2 = s[r2 * D_H + k];
        float v3 = s[r3 * D_H + k];
        float v4 = s[r4 * D_H + k];
        acc += (v1 + v2) + (v3 + v4);
    }
    for (; j < d; j += 4) acc += s[csr[o0 + j] * D_H + k];
    acc += __shfl_xor(acc, 16, 64);
    acc += __shfl_xor(acc, 32, 64);          // all lanes hold full sum
    float dv = dinv[v];
    float h = fmaxf(dv * (acc + s[v * D_H + k]) + b1[k], 0.f);
    // h[v,k] lives in lane (sub*16+k), identical across subs
    float a2 = 0.f;
#pragma unroll
    for (int jj = 0; jj < D_H; ++jj) {
        float hj = __shfl(h, (lane & 48) + jj, 64);
        a2 += hj * w2c[jj];
    }
    if (sub == 0) s2[v * D_H + k] = a2 * dv;
}

// layer-2 pull: h2 = relu(dinv*(gather+self)+b2)
__global__ void pull2_kernel(const float* __restrict__ s, const int* __restrict__ csr,
                             const int* __restrict__ node_off, const int* __restrict__ deg,
                             const float* __restrict__ dinv, const float* __restrict__ b2,
                             float* __restrict__ h) {
    int wave = threadIdx.x >> 6;
    int v = blockIdx.x * 4 + wave;
    if (v >= N_NODES) return;
    int lane = threadIdx.x & 63;
    int sub = lane >> 4;
    int k   = lane & 15;
    int d  = deg[v];
    int o0 = node_off[v];
    float acc = 0.f;
    int j = sub;
    for (; j + 12 < d; j += 16) {
        int r1 = csr[o0 + j];
        int r2 = csr[o0 + j + 4];
        int r3 = csr[o0 + j + 8];
        int r4 = csr[o0 + j + 12];
        float v1 = s[r1 * D_H + k];
        float v2 = s[r2 * D_H + k];
        float v3 = s[r3 * D_H + k];
        float v4 = s[r4 * D_H + k];
        acc += (v1 + v2) + (v3 + v4);
    }
    for (; j < d; j += 4) acc += s[csr[o0 + j] * D_H + k];
    acc += __shfl_xor(acc, 16, 64);
    acc += __shfl_xor(acc, 32, 64);
    if (sub == 0) {
        float o = dinv[v] * (acc + s[v * D_H + k]) + b2[k];
        h[v * D_H + k] = fmaxf(o, 0.f);
    }
}

// batch sorted: starts[g] = first node of graph g; starts[NUM_GRAPHS] = N
__global__ void starts_kernel(const int* __restrict__ batch, int* __restrict__ starts) {
    int v = blockIdx.x * blockDim.x + threadIdx.x;
    if (v >= N_NODES) return;
    int bv = batch[v];
    int prev = (v == 0) ? -1 : batch[v - 1];
    for (int g = prev + 1; g <= bv; ++g) starts[g] = v;
    if (v == N_NODES - 1) {
        for (int g = bv + 1; g <= NUM_GRAPHS; ++g) starts[g] = N_NODES;
    }
}

// one block per graph: mean-pool h rows then sigmoid(pool @ Wl + bl)
__global__ void pool_head_kernel(const float* __restrict__ h, const int* __restrict__ starts,
                                 const float* __restrict__ Wl, const float* __restrict__ bl,
                                 float* __restrict__ out) {
    int g = blockIdx.x;
    int v0 = starts[g], v1 = starts[g + 1];
    int k = threadIdx.x & 15;
    int vi = threadIdx.x >> 4;
    float acc = 0.f;
    for (int v = v0 + vi; v < v1; v += 16) acc += h[v * D_H + k];
    acc += __shfl_xor(acc, 16, 64);
    acc += __shfl_xor(acc, 32, 64);
    __shared__ float sm[4][D_H];
    int lane = threadIdx.x & 63;
    if (lane < 16) sm[threadIdx.x >> 6][k] = acc;
    __syncthreads();
    if (threadIdx.x < 16) {
        float tot = sm[0][k] + sm[1][k] + sm[2][k] + sm[3][k];
        float cntf = (float)(v1 - v0);
        tot /= fmaxf(cntf, 1.0f);
        float p = tot * Wl[k];
        p += __shfl_xor(p, 1, 64);
        p += __shfl_xor(p, 2, 64);
        p += __shfl_xor(p, 4, 64);
        p += __shfl_xor(p, 8, 64);
        if (k == 0) out[g] = 1.0f / (1.0f + expf(-(p + bl[0])));
    }
}

// ---------------- launch ----------------

extern "C" void kernel_launch(void* const* d_in, const int* in_sizes, int n_in,
                              void* d_out, int out_size, void* d_ws, size_t ws_size,
                              hipStream_t stream) {
    const float* x     = (const float*)d_in[0];
    const int*   ei    = (const int*)d_in[1];   // [2, E]: row then col
    const int*   batch = (const int*)d_in[2];
    const float* W1    = (const float*)d_in[3];
    const float* b1    = (const float*)d_in[4];
    const float* W2    = (const float*)d_in[5];
    const float* b2    = (const float*)d_in[6];
    const float* Wl    = (const float*)d_in[7];
    const float* bl    = (const float*)d_in[8];
    float* out = (float*)d_out;

    const int* row = ei;
    const int* col = ei + N_EDGES;

    // workspace layout. Region A is time-shared: {cnt+base} then csr.
    char* wsb = (char*)d_ws;
    size_t o = 0;
    int*   part     = (int*)(wsb + o);   o += (size_t)N_EDGES * 4;          // 12.8 MB
    char*  regionA  = wsb + o;           o += (size_t)N_EDGES * 4;          // 12.8 MB
    int*   cnt      = (int*)regionA;                                        // [NCH][NB]
    int*   base     = (int*)(regionA + (size_t)NCH * NB * 4);               // [NB][NCH]
    int*   csr      = (int*)regionA;                                        // after place
    int*   bcnt     = (int*)(wsb + o);   o += 1024 * 4;
    int*   offs     = (int*)(wsb + o);   o += 1024 * 4;
    int*   node_off = (int*)(wsb + o);   o += 100352 * 4;
    int*   deg      = (int*)(wsb + o);   o += 100352 * 4;
    float* dinv     = (float*)(wsb + o); o += 100352 * 4;
    float* sA       = (float*)(wsb + o); o += (size_t)N_NODES * D_H * 4;    // 6.4 MB
    float* sB       = (float*)(wsb + o); o += (size_t)N_NODES * D_H * 4;    // 6.4 MB
    int*   starts   = (int*)(wsb + o);   o += 1024 * 4;

    const int B = 256;
    const int NVB = (N_NODES + B - 1) / B;   // 391

    // ---- build CSR via deterministic two-level scan (no global cursor atomics) ----
    hist_kernel<<<NCH, B, 0, stream>>>(col, cnt);
    colscan_kernel<<<NB, B, 0, stream>>>(cnt, base, bcnt);
    scan_kernel<<<1, 1024, 0, stream>>>(bcnt, offs);
    place_kernel<<<NCH, B, 0, stream>>>(row, col, base, offs, part);
    csr_kernel<<<NB, B, 0, stream>>>(part, offs, csr, node_off, deg, dinv);

    // ---- layer 1 (+ fused layer-2 GEMM) ----
    xw1_kernel<<<NVB, B, 0, stream>>>(x, W1, dinv, sA);
    pull1_kernel<<<(N_NODES + 3) / 4, B, 0, stream>>>(sA, csr, node_off, deg, dinv,
                                                      b1, W2, sB);
    // ---- layer 2 (h2 reuses sA) ----
    pull2_kernel<<<(N_NODES + 3) / 4, B, 0, stream>>>(sB, csr, node_off, deg, dinv,
                                                      b2, sA);
    // ---- pool + head ----
    starts_kernel<<<NVB, B, 0, stream>>>(batch, starts);
    pool_head_kernel<<<NUM_GRAPHS, B, 0, stream>>>(sA, starts, Wl, bl, out);
}